// Round 1
// 566.590 us; speedup vs baseline: 1.2833x; 1.2833x over previous
//
#include <hip/hip_runtime.h>
#include <math.h>

#define BB 8
#define LL 1024
#define EE 512
#define HH 8
#define HD 64
#define PP 2047

static constexpr float SCALE = 0.04419417382415922f; // 1/sqrt(512)

typedef __bf16 bf16x8 __attribute__((ext_vector_type(8)));
typedef float f32x4 __attribute__((ext_vector_type(4)));
typedef unsigned short u16;
typedef u16 u16x8 __attribute__((ext_vector_type(8)));

#define MFMA16(a, b, c) __builtin_amdgcn_mfma_f32_16x16x32_bf16(a, b, c, 0, 0, 0)

static __device__ __forceinline__ unsigned short f2bfbits(float f) {
    union { float f; unsigned u; } v; v.f = f;
    unsigned r = v.u + 0x7fffu + ((v.u >> 16) & 1u);
    return (unsigned short)(r >> 16);
}
static __device__ __forceinline__ float bfbits2f(unsigned short b) {
    union { unsigned u; float f; } v; v.u = ((unsigned)b) << 16;
    return v.f;
}

static __device__ __forceinline__ u16x8 cvt8(float4 lo, float4 hi) {
    u16x8 r;
    r[0] = f2bfbits(lo.x); r[1] = f2bfbits(lo.y);
    r[2] = f2bfbits(lo.z); r[3] = f2bfbits(lo.w);
    r[4] = f2bfbits(hi.x); r[5] = f2bfbits(hi.y);
    r[6] = f2bfbits(hi.z); r[7] = f2bfbits(hi.w);
    return r;
}

// ---------------------------------------------------------------------------
// Shared MFMA mainloop: C(128x128) = A(128xK) . B(128xK)^T rows, K=512.
// fp32 inputs cast to bf16 in the staging path (reg-staged, XOR-swizzled LDS).
// acc[mt][nt][r] = C[m0 + wr*64 + mt*16 + g*4 + r][n0 + wc*64 + nt*16 + c16]
// ---------------------------------------------------------------------------
template<bool CLAMP>
static __device__ __forceinline__ void gemm128(
    const float* __restrict__ Ag, const float* __restrict__ Bg,
    int m0, int n0, int amax, u16* As, u16* Bs, f32x4 (&acc)[4][4])
{
    const int tid = threadIdx.x;
    const int w = tid >> 6, lane = tid & 63;
    const int g = lane >> 4, c16 = lane & 15;
    const int wr = w >> 1, wc = w & 1;
    const int srow = tid >> 3, su = tid & 7; // staging: 8 lanes per row

#pragma unroll
    for (int i = 0; i < 4; i++)
#pragma unroll
        for (int j = 0; j < 4; j++) acc[i][j] = (f32x4){0.f, 0.f, 0.f, 0.f};

    for (int kt = 0; kt < EE; kt += 64) {
        float4 al[4], ah[4], bl[4], bh[4];
#pragma unroll
        for (int ps = 0; ps < 4; ps++) {
            int row = ps * 32 + srow;
            int ar = m0 + row;
            if (CLAMP) ar = ar > amax ? amax : ar;
            const float* ap = Ag + (size_t)ar * EE + kt + su * 8;
            al[ps] = *(const float4*)ap;
            ah[ps] = *(const float4*)(ap + 4);
            const float* bp = Bg + (size_t)(n0 + row) * EE + kt + su * 8;
            bl[ps] = *(const float4*)bp;
            bh[ps] = *(const float4*)(bp + 4);
        }
        __syncthreads(); // previous iteration's reads done
#pragma unroll
        for (int ps = 0; ps < 4; ps++) {
            int row = ps * 32 + srow;
            int off = row * 64 + ((su ^ (row & 7)) << 3); // swizzled 16B unit
            *(u16x8*)&As[off] = cvt8(al[ps], ah[ps]);
            *(u16x8*)&Bs[off] = cvt8(bl[ps], bh[ps]);
        }
        __syncthreads();
#pragma unroll
        for (int kk = 0; kk < 2; kk++) {
            bf16x8 av[4], bv[4];
#pragma unroll
            for (int mt = 0; mt < 4; mt++) {
                int r0 = wr * 64 + mt * 16 + c16;
                av[mt] = *(const bf16x8*)&As[r0 * 64 + (((kk * 4 + g) ^ (r0 & 7)) << 3)];
            }
#pragma unroll
            for (int nt = 0; nt < 4; nt++) {
                int r0 = wc * 64 + nt * 16 + c16;
                bv[nt] = *(const bf16x8*)&Bs[r0 * 64 + (((kk * 4 + g) ^ (r0 & 7)) << 3)];
            }
#pragma unroll
            for (int mt = 0; mt < 4; mt++)
#pragma unroll
                for (int nt = 0; nt < 4; nt++)
                    acc[mt][nt] = MFMA16(av[mt], bv[nt], acc[mt][nt]);
        }
    }
}

// ---------------------------------------------------------------------------
// qkv: (B*L,E) @ (3E,E)^T; epilogue splits q/k/v, applies (q+u)*scale etc.
// ---------------------------------------------------------------------------
__global__ __launch_bounds__(256) void qkv_kernel(
    const float* __restrict__ x,      // (B*L, E)
    const float* __restrict__ wq,     // (3E, E)
    const float* __restrict__ ubias,  // flat 512
    const float* __restrict__ vbias,  // flat 512
    unsigned short* __restrict__ Qu,  // (B,H,L,HD) bf16, (q+u)*scale
    unsigned short* __restrict__ Qv,  // (B,H,L,HD) bf16, (q+v)*scale
    unsigned short* __restrict__ Kw,  // (B,H,L,HD) bf16
    unsigned short* __restrict__ Vt)  // (B,H,HD,L) bf16 (transposed!)
{
    __shared__ u16 As[128 * 64];
    __shared__ u16 Bs[128 * 64];
    const int m0 = blockIdx.y * 128, n0 = blockIdx.x * 128;
    f32x4 acc[4][4];
    gemm128<false>(x, wq, m0, n0, 0, As, Bs, acc);

    const int tid = threadIdx.x;
    const int w = tid >> 6, lane = tid & 63;
    const int g = lane >> 4, c16 = lane & 15;
    const int wr = w >> 1, wc = w & 1;

#pragma unroll
    for (int mt = 0; mt < 4; mt++) {
#pragma unroll
        for (int r = 0; r < 4; r++) {
            int m = m0 + wr * 64 + mt * 16 + g * 4 + r;
            int b = m >> 10, l = m & 1023;
#pragma unroll
            for (int nt = 0; nt < 4; nt++) {
                int n = n0 + wc * 64 + nt * 16 + c16;
                int h = n / 192;
                int rr = n - h * 192;
                int cls = rr >> 6;
                int d = rr & 63;
                float v = acc[mt][nt][r];
                if (cls == 0) {
                    size_t idx = ((size_t)(b * HH + h) * LL + l) * HD + d;
                    Qu[idx] = f2bfbits((v + ubias[h * 64 + d]) * SCALE);
                    Qv[idx] = f2bfbits((v + vbias[h * 64 + d]) * SCALE);
                } else if (cls == 1) {
                    Kw[((size_t)(b * HH + h) * LL + l) * HD + d] = f2bfbits(v);
                } else {
                    Vt[((size_t)(b * HH + h) * HD + d) * LL + l] = f2bfbits(v);
                }
            }
        }
    }
}

// ---------------------------------------------------------------------------
// posk: (P,E) @ (E,E)^T -> (H,P,HD) bf16; M=2047 needs row clamp/guard.
// ---------------------------------------------------------------------------
__global__ __launch_bounds__(256) void posk_kernel(
    const float* __restrict__ pe,  // (P, E)
    const float* __restrict__ wp,  // (E, E)
    unsigned short* __restrict__ pko)  // (H, P, HD) bf16
{
    __shared__ u16 As[128 * 64];
    __shared__ u16 Bs[128 * 64];
    const int m0 = blockIdx.y * 128, n0 = blockIdx.x * 128;
    f32x4 acc[4][4];
    gemm128<true>(pe, wp, m0, n0, PP - 1, As, Bs, acc);

    const int tid = threadIdx.x;
    const int w = tid >> 6, lane = tid & 63;
    const int g = lane >> 4, c16 = lane & 15;
    const int wr = w >> 1, wc = w & 1;

#pragma unroll
    for (int mt = 0; mt < 4; mt++) {
#pragma unroll
        for (int r = 0; r < 4; r++) {
            int p = m0 + wr * 64 + mt * 16 + g * 4 + r;
            if (p >= PP) continue;
#pragma unroll
            for (int nt = 0; nt < 4; nt++) {
                int n = n0 + wc * 64 + nt * 16 + c16;
                int h = n >> 6, d = n & 63;
                pko[((size_t)h * PP + p) * HD + d] = f2bfbits(acc[mt][nt][r]);
            }
        }
    }
}

// ---------------------------------------------------------------------------
// outproj: (B*L,E) @ (E,E)^T + bias -> fp32 out
// ---------------------------------------------------------------------------
__global__ __launch_bounds__(256) void outproj_kernel(
    const float* __restrict__ ctx,  // (B*L, E)
    const float* __restrict__ wo,   // (E, E)
    const float* __restrict__ bias, // (E,)
    float* __restrict__ out)        // (B*L, E)
{
    __shared__ u16 As[128 * 64];
    __shared__ u16 Bs[128 * 64];
    const int m0 = blockIdx.y * 128, n0 = blockIdx.x * 128;
    f32x4 acc[4][4];
    gemm128<false>(ctx, wo, m0, n0, 0, As, Bs, acc);

    const int tid = threadIdx.x;
    const int w = tid >> 6, lane = tid & 63;
    const int g = lane >> 4, c16 = lane & 15;
    const int wr = w >> 1, wc = w & 1;

#pragma unroll
    for (int mt = 0; mt < 4; mt++) {
#pragma unroll
        for (int r = 0; r < 4; r++) {
            int m = m0 + wr * 64 + mt * 16 + g * 4 + r;
#pragma unroll
            for (int nt = 0; nt < 4; nt++) {
                int n = n0 + wc * 64 + nt * 16 + c16;
                out[(size_t)m * EE + n] = acc[mt][nt][r] + bias[n];
            }
        }
    }
}

// ---------------------------------------------------------------------------
// MFMA fused attention. Block = (b, h, 16 q-rows); 4 waves split k (256 each).
// logit[q,k] = Qu[q].K[k] + Qv[q].pk[k-q+1023]; softmax; attn write; PV.
// ---------------------------------------------------------------------------
__global__ __launch_bounds__(256, 3) void attn_kernel(
    const unsigned short* __restrict__ Qu, const unsigned short* __restrict__ Qv,
    const unsigned short* __restrict__ Kw, const unsigned short* __restrict__ Vt,
    const unsigned short* __restrict__ pk,  // (H,P,HD) bf16
    float* __restrict__ attn,               // (B,H,L,L)
    float* __restrict__ ctx)                // (B,L,E)
{
    const int b = blockIdx.z, h = blockIdx.y, q0 = blockIdx.x * 16;
    const int tid = threadIdx.x;
    const int w = tid >> 6, lane = tid & 63;
    const int g = lane >> 4, c16 = lane & 15;
    const int bh = b * HH + h;

    __shared__ unsigned short BDG[4][16 * 152];  // per-wave: BD window gemm / P staging
    __shared__ float SMmax[4][16];
    __shared__ float SMsum[4][16];
    __shared__ float CTX[4][16 * 68];

    // resident A-fragments (A[m=lane&15][k=g*8+j]): direct 16B global loads
    const unsigned short* qub = Qu + ((size_t)bh * LL + q0 + c16) * HD + g * 8;
    const unsigned short* qvb = Qv + ((size_t)bh * LL + q0 + c16) * HD + g * 8;
    bf16x8 au0 = *(const bf16x8*)qub;
    bf16x8 au1 = *(const bf16x8*)(qub + 32);
    bf16x8 av0 = *(const bf16x8*)qvb;
    bf16x8 av1 = *(const bf16x8*)(qvb + 32);

    f32x4 lg[16];
#pragma unroll
    for (int t = 0; t < 16; t++) lg[t] = (f32x4){0.f, 0.f, 0.f, 0.f};

    const unsigned short* kbase  = Kw + (size_t)bh * LL * HD;
    const unsigned short* pkbase = pk + (size_t)h * PP * HD;

#pragma unroll
    for (int p = 0; p < 2; p++) {
        const int kp = w * 256 + p * 128;
        const int pstart = kp - q0 + 1008;  // window col 0 -> p index
        // BD window gemm: 16 q x 144 cols, staged bf16 in LDS
#pragma unroll
        for (int ct = 0; ct < 9; ct++) {
            int prow = pstart + ct * 16 + c16;
            prow = prow > (PP - 1) ? (PP - 1) : prow;  // col 143 pad, never gathered
            const unsigned short* pb = pkbase + (size_t)prow * HD + g * 8;
            f32x4 acc = (f32x4){0.f, 0.f, 0.f, 0.f};
            acc = MFMA16(av0, *(const bf16x8*)pb, acc);
            acc = MFMA16(av1, *(const bf16x8*)(pb + 32), acc);
#pragma unroll
            for (int r = 0; r < 4; r++)
                BDG[w][(g * 4 + r) * 152 + ct * 16 + c16] = f2bfbits(acc[r]);
        }
        // AC: B-frag = K rows, direct global 16B loads
#pragma unroll
        for (int jt = 0; jt < 8; jt++) {
            const unsigned short* kb = kbase + (size_t)(kp + jt * 16 + c16) * HD + g * 8;
            int t = p * 8 + jt;
            lg[t] = MFMA16(au0, *(const bf16x8*)kb, lg[t]);
            lg[t] = MFMA16(au1, *(const bf16x8*)(kb + 32), lg[t]);
        }
        __syncthreads();
        // diagonal gather: BD[i][j] = BDG[i][j - i + 15]
#pragma unroll
        for (int jt = 0; jt < 8; jt++) {
            int t = p * 8 + jt;
#pragma unroll
            for (int r = 0; r < 4; r++) {
                int i = g * 4 + r;
                int c = jt * 16 + c16 - i + 15;
                lg[t][r] += bfbits2f(BDG[w][i * 152 + c]);
            }
        }
        __syncthreads();
    }

    // ---- softmax over full 1024 keys ----
    float M[4], Sv[4], inv[4];
#pragma unroll
    for (int r = 0; r < 4; r++) {
        float m = lg[0][r];
#pragma unroll
        for (int t = 1; t < 16; t++) m = fmaxf(m, lg[t][r]);
        M[r] = m;
    }
#pragma unroll
    for (int off = 8; off >= 1; off >>= 1)
#pragma unroll
        for (int r = 0; r < 4; r++) M[r] = fmaxf(M[r], __shfl_xor(M[r], off, 16));
    if (c16 == 0) {
#pragma unroll
        for (int r = 0; r < 4; r++) SMmax[w][g * 4 + r] = M[r];
    }
    __syncthreads();
#pragma unroll
    for (int r = 0; r < 4; r++) {
        int row = g * 4 + r;
        M[r] = fmaxf(fmaxf(SMmax[0][row], SMmax[1][row]),
                     fmaxf(SMmax[2][row], SMmax[3][row]));
        Sv[r] = 0.f;
    }
#pragma unroll
    for (int t = 0; t < 16; t++)
#pragma unroll
        for (int r = 0; r < 4; r++) {
            float e = __expf(lg[t][r] - M[r]);
            lg[t][r] = e;
            Sv[r] += e;
        }
#pragma unroll
    for (int off = 8; off >= 1; off >>= 1)
#pragma unroll
        for (int r = 0; r < 4; r++) Sv[r] += __shfl_xor(Sv[r], off, 16);
    if (c16 == 0) {
#pragma unroll
        for (int r = 0; r < 4; r++) SMsum[w][g * 4 + r] = Sv[r];
    }
    __syncthreads();
#pragma unroll
    for (int r = 0; r < 4; r++) {
        int row = g * 4 + r;
        inv[r] = 1.0f / (SMsum[0][row] + SMsum[1][row] + SMsum[2][row] + SMsum[3][row]);
    }

    // ---- normalize + write attn ----
    float* arow = attn + (size_t)bh * LL * LL;
#pragma unroll
    for (int t = 0; t < 16; t++)
#pragma unroll
        for (int r = 0; r < 4; r++) {
            float pr = lg[t][r] * inv[r];
            lg[t][r] = pr;
            arow[(size_t)(q0 + g * 4 + r) * LL + w * 256 + t * 16 + c16] = pr;
        }

    // ---- PV: ctx[q][d] = sum_k P[q,k] V[k,d], B from transposed V ----
    f32x4 cacc[4];
#pragma unroll
    for (int nt = 0; nt < 4; nt++) cacc[nt] = (f32x4){0.f, 0.f, 0.f, 0.f};

#pragma unroll
    for (int p = 0; p < 2; p++) {
        const int kp = w * 256 + p * 128;
        __syncthreads();
        // stage P (C-layout -> A-layout via LDS), bf16
#pragma unroll
        for (int jt = 0; jt < 8; jt++) {
            int t = p * 8 + jt;
#pragma unroll
            for (int r = 0; r < 4; r++)
                BDG[w][(g * 4 + r) * 152 + jt * 16 + c16] = f2bfbits(lg[t][r]);
        }
        __syncthreads();
        bf16x8 pa[4];
#pragma unroll
        for (int kk = 0; kk < 4; kk++)
            pa[kk] = *(const bf16x8*)&BDG[w][c16 * 152 + kk * 32 + g * 8];
#pragma unroll
        for (int kk = 0; kk < 4; kk++) {
#pragma unroll
            for (int nt = 0; nt < 4; nt++) {
                const unsigned short* vb =
                    Vt + ((size_t)bh * HD + nt * 16 + c16) * LL + kp + kk * 32 + g * 8;
                cacc[nt] = MFMA16(pa[kk], *(const bf16x8*)vb, cacc[nt]);
            }
        }
    }

    // ---- cross-wave ctx reduction ----
    __syncthreads();
#pragma unroll
    for (int nt = 0; nt < 4; nt++)
#pragma unroll
        for (int r = 0; r < 4; r++)
            CTX[w][(g * 4 + r) * 68 + nt * 16 + c16] = cacc[nt][r];
    __syncthreads();
    {
        int row = tid >> 4, d4 = (tid & 15) * 4;
        f32x4 s = *(const f32x4*)&CTX[0][row * 68 + d4];
        s += *(const f32x4*)&CTX[1][row * 68 + d4];
        s += *(const f32x4*)&CTX[2][row * 68 + d4];
        s += *(const f32x4*)&CTX[3][row * 68 + d4];
        *(f32x4*)&ctx[((size_t)b * LL + q0 + row) * EE + h * HD + d4] = s;
    }
}

// ---------------------------------------------------------------------------
extern "C" void kernel_launch(void* const* d_in, const int* in_sizes, int n_in,
                              void* d_out, int out_size, void* d_ws, size_t ws_size,
                              hipStream_t stream)
{
    const float* x   = (const float*)d_in[0];
    const float* pe  = (const float*)d_in[1];
    const float* ipw = (const float*)d_in[2];
    const float* lpw = (const float*)d_in[3];
    const float* opw = (const float*)d_in[4];
    const float* opb = (const float*)d_in[5];
    const float* pbu = (const float*)d_in[6];
    const float* pbv = (const float*)d_in[7];

    float* out  = (float*)d_out;                          // (B,L,E)
    float* attn = (float*)d_out + (size_t)BB * LL * EE;   // (B,H,L,L)

    const size_t NQ = (size_t)BB * HH * LL * HD;  // 4194304
    float* ctx = (float*)d_ws;                    // 16 MB fp32
    unsigned short* wsu = (unsigned short*)(ctx + (size_t)BB * LL * EE);
    unsigned short* Qu = wsu; wsu += NQ;
    unsigned short* Qv = wsu; wsu += NQ;
    unsigned short* Kw = wsu; wsu += NQ;
    unsigned short* Vt = wsu; wsu += NQ;
    unsigned short* pkb = wsu; wsu += (size_t)HH * PP * HD;

    qkv_kernel<<<dim3(12, 64), 256, 0, stream>>>(x, ipw, pbu, pbv, Qu, Qv, Kw, Vt);
    posk_kernel<<<dim3(4, 16), 256, 0, stream>>>(pe, lpw, pkb);
    attn_kernel<<<dim3(64, 8, 8), 256, 0, stream>>>(Qu, Qv, Kw, Vt, pkb, attn, ctx);
    outproj_kernel<<<dim3(4, 64), 256, 0, stream>>>(ctx, opw, opb, out);
}

// Round 2
// 541.189 us; speedup vs baseline: 1.3435x; 1.0469x over previous
//
#include <hip/hip_runtime.h>
#include <math.h>

#define BB 8
#define LL 1024
#define EE 512
#define HH 8
#define HD 64
#define PP 2047

static constexpr float SCALE = 0.04419417382415922f; // 1/sqrt(512)

typedef __bf16 bf16x8 __attribute__((ext_vector_type(8)));
typedef float f32x4 __attribute__((ext_vector_type(4)));
typedef unsigned short u16;
typedef u16 u16x8 __attribute__((ext_vector_type(8)));
typedef u16 u16x4 __attribute__((ext_vector_type(4)));

#define MFMA16(a, b, c) __builtin_amdgcn_mfma_f32_16x16x32_bf16(a, b, c, 0, 0, 0)

static __device__ __forceinline__ unsigned short f2bfbits(float f) {
    union { float f; unsigned u; } v; v.f = f;
    unsigned r = v.u + 0x7fffu + ((v.u >> 16) & 1u);
    return (unsigned short)(r >> 16);
}
static __device__ __forceinline__ float bfbits2f(unsigned short b) {
    union { unsigned u; float f; } v; v.u = ((unsigned)b) << 16;
    return v.f;
}

static __device__ __forceinline__ u16x8 cvt8(float4 lo, float4 hi) {
    u16x8 r;
    r[0] = f2bfbits(lo.x); r[1] = f2bfbits(lo.y);
    r[2] = f2bfbits(lo.z); r[3] = f2bfbits(lo.w);
    r[4] = f2bfbits(hi.x); r[5] = f2bfbits(hi.y);
    r[6] = f2bfbits(hi.z); r[7] = f2bfbits(hi.w);
    return r;
}

// async global(16B/lane) -> LDS, wave-uniform LDS base + lane*16
static __device__ __forceinline__ void gload_lds16(const u16* g, u16* l) {
    __builtin_amdgcn_global_load_lds(
        (const __attribute__((address_space(1))) unsigned int*)g,
        (__attribute__((address_space(3))) unsigned int*)l, 16, 0, 0);
}

// ---------------------------------------------------------------------------
// Fused one-shot fp32 -> bf16 cast of all GEMM inputs.
// cum: x 4194304 | pe 1048064 | ipw 786432 | lpw 262144 | opw 262144
// ---------------------------------------------------------------------------
__global__ __launch_bounds__(256) void cast_all(
    const float* __restrict__ x, const float* __restrict__ pe,
    const float* __restrict__ ipw, const float* __restrict__ lpw,
    const float* __restrict__ opw,
    u16* __restrict__ Xb, u16* __restrict__ Pb, u16* __restrict__ Wqb,
    u16* __restrict__ Wpb, u16* __restrict__ Wob)
{
    size_t e = ((size_t)blockIdx.x * 256 + threadIdx.x) * 8;
    const float* src; u16* dst; size_t off;
    if (e < 4194304)      { src = x;   dst = Xb;  off = e; }
    else if (e < 5242368) { src = pe;  dst = Pb;  off = e - 4194304; }
    else if (e < 6028800) { src = ipw; dst = Wqb; off = e - 5242368; }
    else if (e < 6290944) { src = lpw; dst = Wpb; off = e - 6028800; }
    else if (e < 6553088) { src = opw; dst = Wob; off = e - 6290944; }
    else return;
    float4 lo = *(const float4*)&src[off];
    float4 hi = *(const float4*)&src[off + 4];
    *(u16x8*)&dst[off] = cvt8(lo, hi);
}

// ---------------------------------------------------------------------------
// bf16 MFMA mainloop: C(128x128) = A(128xK) . B(128xK)^T rows, K=512.
// global_load_lds(16B) staging, linear LDS dest, XOR-swizzled global source
// + matching XOR on ds_read side (rule: both-sides-or-neither).
// acc[mt][nt][r] = C[m0 + wr*64 + mt*16 + g*4 + r][n0 + wc*64 + nt*16 + c16]
// ---------------------------------------------------------------------------
template<bool CLAMP>
static __device__ __forceinline__ void gemm128b(
    const u16* __restrict__ Ab, const u16* __restrict__ Bb,
    int m0, int n0, int amax, u16* As, u16* Bs, f32x4 (&acc)[4][4])
{
    const int tid = threadIdx.x;
    const int w = tid >> 6, lane = tid & 63;
    const int g = lane >> 4, c16 = lane & 15;
    const int wr = w >> 1, wc = w & 1;

#pragma unroll
    for (int i = 0; i < 4; i++)
#pragma unroll
        for (int j = 0; j < 4; j++) acc[i][j] = (f32x4){0.f, 0.f, 0.f, 0.f};

    // staging geometry: 16B unit U = j*256 + tid; row = U>>3, col-unit = U&7,
    // source col-unit swizzled by row&7; LDS stays linear (HW lane*16 order).
    int arow[4], brow[4], cs8[4], ldsu[4];
#pragma unroll
    for (int j = 0; j < 4; j++) {
        int U = j * 256 + tid;
        int row = U >> 3, cu = U & 7;
        cs8[j] = (cu ^ (row & 7)) * 8;
        int ar = m0 + row;
        if (CLAMP) ar = ar > amax ? amax : ar;
        arow[j] = ar;
        brow[j] = n0 + row;
        ldsu[j] = (j * 256 + (w << 6)) * 8; // wave-uniform LDS base (u16 elems)
    }

    for (int kt = 0; kt < EE; kt += 64) {
#pragma unroll
        for (int j = 0; j < 4; j++) {
            gload_lds16(Ab + (size_t)arow[j] * EE + kt + cs8[j], As + ldsu[j]);
            gload_lds16(Bb + (size_t)brow[j] * EE + kt + cs8[j], Bs + ldsu[j]);
        }
        __syncthreads(); // drains vmcnt -> tiles resident
#pragma unroll
        for (int kk = 0; kk < 2; kk++) {
            bf16x8 av[4], bv[4];
#pragma unroll
            for (int mt = 0; mt < 4; mt++) {
                int r0 = wr * 64 + mt * 16 + c16;
                av[mt] = *(const bf16x8*)&As[r0 * 64 + (((kk * 4 + g) ^ (r0 & 7)) << 3)];
            }
#pragma unroll
            for (int nt = 0; nt < 4; nt++) {
                int r0 = wc * 64 + nt * 16 + c16;
                bv[nt] = *(const bf16x8*)&Bs[r0 * 64 + (((kk * 4 + g) ^ (r0 & 7)) << 3)];
            }
#pragma unroll
            for (int mt = 0; mt < 4; mt++)
#pragma unroll
                for (int nt = 0; nt < 4; nt++)
                    acc[mt][nt] = MFMA16(av[mt], bv[nt], acc[mt][nt]);
        }
        __syncthreads(); // all reads done before next stage overwrites
    }
}

// ---------------------------------------------------------------------------
// qkv: (B*L,E) @ (3E,E)^T; epilogue splits q/k/v, applies (q+u)*scale etc.
// ---------------------------------------------------------------------------
__global__ __launch_bounds__(256) void qkv_kernel(
    const u16* __restrict__ xb,       // (B*L, E) bf16
    const u16* __restrict__ wq,       // (3E, E) bf16
    const float* __restrict__ ubias,  // flat 512
    const float* __restrict__ vbias,  // flat 512
    unsigned short* __restrict__ Qu,  // (B,H,L,HD) bf16, (q+u)*scale
    unsigned short* __restrict__ Qv,  // (B,H,L,HD) bf16, (q+v)*scale
    unsigned short* __restrict__ Kw,  // (B,H,L,HD) bf16
    unsigned short* __restrict__ Vt)  // (B,H,HD,L) bf16 (transposed!)
{
    __shared__ u16 As[128 * 64];
    __shared__ u16 Bs[128 * 64];
    const int m0 = blockIdx.y * 128, n0 = blockIdx.x * 128;
    f32x4 acc[4][4];
    gemm128b<false>(xb, wq, m0, n0, 0, As, Bs, acc);

    const int tid = threadIdx.x;
    const int w = tid >> 6, lane = tid & 63;
    const int g = lane >> 4, c16 = lane & 15;
    const int wr = w >> 1, wc = w & 1;

#pragma unroll
    for (int mt = 0; mt < 4; mt++) {
#pragma unroll
        for (int r = 0; r < 4; r++) {
            int m = m0 + wr * 64 + mt * 16 + g * 4 + r;
            int b = m >> 10, l = m & 1023;
#pragma unroll
            for (int nt = 0; nt < 4; nt++) {
                int n = n0 + wc * 64 + nt * 16 + c16;
                int h = n / 192;
                int rr = n - h * 192;
                int cls = rr >> 6;
                int d = rr & 63;
                float v = acc[mt][nt][r];
                if (cls == 0) {
                    size_t idx = ((size_t)(b * HH + h) * LL + l) * HD + d;
                    Qu[idx] = f2bfbits((v + ubias[h * 64 + d]) * SCALE);
                    Qv[idx] = f2bfbits((v + vbias[h * 64 + d]) * SCALE);
                } else if (cls == 1) {
                    Kw[((size_t)(b * HH + h) * LL + l) * HD + d] = f2bfbits(v);
                } else {
                    Vt[((size_t)(b * HH + h) * HD + d) * LL + l] = f2bfbits(v);
                }
            }
        }
    }
}

// ---------------------------------------------------------------------------
// posk: (P,E) @ (E,E)^T -> (H,P,HD) bf16; M=2047 needs row clamp/guard.
// ---------------------------------------------------------------------------
__global__ __launch_bounds__(256) void posk_kernel(
    const u16* __restrict__ peb,  // (P, E) bf16
    const u16* __restrict__ wp,   // (E, E) bf16
    unsigned short* __restrict__ pko)  // (H, P, HD) bf16
{
    __shared__ u16 As[128 * 64];
    __shared__ u16 Bs[128 * 64];
    const int m0 = blockIdx.y * 128, n0 = blockIdx.x * 128;
    f32x4 acc[4][4];
    gemm128b<true>(peb, wp, m0, n0, PP - 1, As, Bs, acc);

    const int tid = threadIdx.x;
    const int w = tid >> 6, lane = tid & 63;
    const int g = lane >> 4, c16 = lane & 15;
    const int wr = w >> 1, wc = w & 1;

#pragma unroll
    for (int mt = 0; mt < 4; mt++) {
#pragma unroll
        for (int r = 0; r < 4; r++) {
            int p = m0 + wr * 64 + mt * 16 + g * 4 + r;
            if (p >= PP) continue;
#pragma unroll
            for (int nt = 0; nt < 4; nt++) {
                int n = n0 + wc * 64 + nt * 16 + c16;
                int h = n >> 6, d = n & 63;
                pko[((size_t)h * PP + p) * HD + d] = f2bfbits(acc[mt][nt][r]);
            }
        }
    }
}

// ---------------------------------------------------------------------------
// outproj: (B*L,E)bf16 @ (E,E)^T bf16 + bias -> fp32 out
// ---------------------------------------------------------------------------
__global__ __launch_bounds__(256) void outproj_kernel(
    const u16* __restrict__ ctxb,   // (B*L, E) bf16
    const u16* __restrict__ wo,     // (E, E) bf16
    const float* __restrict__ bias, // (E,)
    float* __restrict__ out)        // (B*L, E)
{
    __shared__ u16 As[128 * 64];
    __shared__ u16 Bs[128 * 64];
    const int m0 = blockIdx.y * 128, n0 = blockIdx.x * 128;
    f32x4 acc[4][4];
    gemm128b<false>(ctxb, wo, m0, n0, 0, As, Bs, acc);

    const int tid = threadIdx.x;
    const int w = tid >> 6, lane = tid & 63;
    const int g = lane >> 4, c16 = lane & 15;
    const int wr = w >> 1, wc = w & 1;

#pragma unroll
    for (int mt = 0; mt < 4; mt++) {
#pragma unroll
        for (int r = 0; r < 4; r++) {
            int m = m0 + wr * 64 + mt * 16 + g * 4 + r;
#pragma unroll
            for (int nt = 0; nt < 4; nt++) {
                int n = n0 + wc * 64 + nt * 16 + c16;
                out[(size_t)m * EE + n] = acc[mt][nt][r] + bias[n];
            }
        }
    }
}

// ---------------------------------------------------------------------------
// MFMA fused attention. Block = (b, h, 16 q-rows); 4 waves split k (256 each).
// logit[q,k] = Qu[q].K[k] + Qv[q].pk[k-q+1023]; softmax; attn write; PV.
// ctx is written bf16 (consumed by outproj's bf16 MFMA path).
// ---------------------------------------------------------------------------
__global__ __launch_bounds__(256, 3) void attn_kernel(
    const unsigned short* __restrict__ Qu, const unsigned short* __restrict__ Qv,
    const unsigned short* __restrict__ Kw, const unsigned short* __restrict__ Vt,
    const unsigned short* __restrict__ pk,  // (H,P,HD) bf16
    float* __restrict__ attn,               // (B,H,L,L)
    u16* __restrict__ ctxb)                 // (B,L,E) bf16
{
    const int b = blockIdx.z, h = blockIdx.y, q0 = blockIdx.x * 16;
    const int tid = threadIdx.x;
    const int w = tid >> 6, lane = tid & 63;
    const int g = lane >> 4, c16 = lane & 15;
    const int bh = b * HH + h;

    __shared__ unsigned short BDG[4][16 * 152];  // per-wave: BD window gemm / P staging
    __shared__ float SMmax[4][16];
    __shared__ float SMsum[4][16];
    __shared__ float CTX[4][16 * 68];

    // resident A-fragments (A[m=lane&15][k=g*8+j]): direct 16B global loads
    const unsigned short* qub = Qu + ((size_t)bh * LL + q0 + c16) * HD + g * 8;
    const unsigned short* qvb = Qv + ((size_t)bh * LL + q0 + c16) * HD + g * 8;
    bf16x8 au0 = *(const bf16x8*)qub;
    bf16x8 au1 = *(const bf16x8*)(qub + 32);
    bf16x8 av0 = *(const bf16x8*)qvb;
    bf16x8 av1 = *(const bf16x8*)(qvb + 32);

    f32x4 lg[16];
#pragma unroll
    for (int t = 0; t < 16; t++) lg[t] = (f32x4){0.f, 0.f, 0.f, 0.f};

    const unsigned short* kbase  = Kw + (size_t)bh * LL * HD;
    const unsigned short* pkbase = pk + (size_t)h * PP * HD;

#pragma unroll
    for (int p = 0; p < 2; p++) {
        const int kp = w * 256 + p * 128;
        const int pstart = kp - q0 + 1008;  // window col 0 -> p index
        // BD window gemm: 16 q x 144 cols, staged bf16 in LDS
#pragma unroll
        for (int ct = 0; ct < 9; ct++) {
            int prow = pstart + ct * 16 + c16;
            prow = prow > (PP - 1) ? (PP - 1) : prow;  // col 143 pad, never gathered
            const unsigned short* pb = pkbase + (size_t)prow * HD + g * 8;
            f32x4 acc = (f32x4){0.f, 0.f, 0.f, 0.f};
            acc = MFMA16(av0, *(const bf16x8*)pb, acc);
            acc = MFMA16(av1, *(const bf16x8*)(pb + 32), acc);
#pragma unroll
            for (int r = 0; r < 4; r++)
                BDG[w][(g * 4 + r) * 152 + ct * 16 + c16] = f2bfbits(acc[r]);
        }
        // AC: B-frag = K rows, direct global 16B loads
#pragma unroll
        for (int jt = 0; jt < 8; jt++) {
            const unsigned short* kb = kbase + (size_t)(kp + jt * 16 + c16) * HD + g * 8;
            int t = p * 8 + jt;
            lg[t] = MFMA16(au0, *(const bf16x8*)kb, lg[t]);
            lg[t] = MFMA16(au1, *(const bf16x8*)(kb + 32), lg[t]);
        }
        __syncthreads();
        // diagonal gather: BD[i][j] = BDG[i][j - i + 15]
#pragma unroll
        for (int jt = 0; jt < 8; jt++) {
            int t = p * 8 + jt;
#pragma unroll
            for (int r = 0; r < 4; r++) {
                int i = g * 4 + r;
                int c = jt * 16 + c16 - i + 15;
                lg[t][r] += bfbits2f(BDG[w][i * 152 + c]);
            }
        }
        __syncthreads();
    }

    // ---- softmax over full 1024 keys ----
    float M[4], Sv[4], inv[4];
#pragma unroll
    for (int r = 0; r < 4; r++) {
        float m = lg[0][r];
#pragma unroll
        for (int t = 1; t < 16; t++) m = fmaxf(m, lg[t][r]);
        M[r] = m;
    }
#pragma unroll
    for (int off = 8; off >= 1; off >>= 1)
#pragma unroll
        for (int r = 0; r < 4; r++) M[r] = fmaxf(M[r], __shfl_xor(M[r], off, 16));
    if (c16 == 0) {
#pragma unroll
        for (int r = 0; r < 4; r++) SMmax[w][g * 4 + r] = M[r];
    }
    __syncthreads();
#pragma unroll
    for (int r = 0; r < 4; r++) {
        int row = g * 4 + r;
        M[r] = fmaxf(fmaxf(SMmax[0][row], SMmax[1][row]),
                     fmaxf(SMmax[2][row], SMmax[3][row]));
        Sv[r] = 0.f;
    }
#pragma unroll
    for (int t = 0; t < 16; t++)
#pragma unroll
        for (int r = 0; r < 4; r++) {
            float e = __expf(lg[t][r] - M[r]);
            lg[t][r] = e;
            Sv[r] += e;
        }
#pragma unroll
    for (int off = 8; off >= 1; off >>= 1)
#pragma unroll
        for (int r = 0; r < 4; r++) Sv[r] += __shfl_xor(Sv[r], off, 16);
    if (c16 == 0) {
#pragma unroll
        for (int r = 0; r < 4; r++) SMsum[w][g * 4 + r] = Sv[r];
    }
    __syncthreads();
#pragma unroll
    for (int r = 0; r < 4; r++) {
        int row = g * 4 + r;
        inv[r] = 1.0f / (SMsum[0][row] + SMsum[1][row] + SMsum[2][row] + SMsum[3][row]);
    }

    // ---- normalize + write attn ----
    float* arow = attn + (size_t)bh * LL * LL;
#pragma unroll
    for (int t = 0; t < 16; t++)
#pragma unroll
        for (int r = 0; r < 4; r++) {
            float pr = lg[t][r] * inv[r];
            lg[t][r] = pr;
            arow[(size_t)(q0 + g * 4 + r) * LL + w * 256 + t * 16 + c16] = pr;
        }

    // ---- PV: ctx[q][d] = sum_k P[q,k] V[k,d], B from transposed V ----
    f32x4 cacc[4];
#pragma unroll
    for (int nt = 0; nt < 4; nt++) cacc[nt] = (f32x4){0.f, 0.f, 0.f, 0.f};

#pragma unroll
    for (int p = 0; p < 2; p++) {
        const int kp = w * 256 + p * 128;
        __syncthreads();
        // stage P (C-layout -> A-layout via LDS), bf16
#pragma unroll
        for (int jt = 0; jt < 8; jt++) {
            int t = p * 8 + jt;
#pragma unroll
            for (int r = 0; r < 4; r++)
                BDG[w][(g * 4 + r) * 152 + jt * 16 + c16] = f2bfbits(lg[t][r]);
        }
        __syncthreads();
        bf16x8 pa[4];
#pragma unroll
        for (int kk = 0; kk < 4; kk++)
            pa[kk] = *(const bf16x8*)&BDG[w][c16 * 152 + kk * 32 + g * 8];
#pragma unroll
        for (int kk = 0; kk < 4; kk++) {
#pragma unroll
            for (int nt = 0; nt < 4; nt++) {
                const unsigned short* vb =
                    Vt + ((size_t)bh * HD + nt * 16 + c16) * LL + kp + kk * 32 + g * 8;
                cacc[nt] = MFMA16(pa[kk], *(const bf16x8*)vb, cacc[nt]);
            }
        }
    }

    // ---- cross-wave ctx reduction (bf16 output) ----
    __syncthreads();
#pragma unroll
    for (int nt = 0; nt < 4; nt++)
#pragma unroll
        for (int r = 0; r < 4; r++)
            CTX[w][(g * 4 + r) * 68 + nt * 16 + c16] = cacc[nt][r];
    __syncthreads();
    {
        int row = tid >> 4, d4 = (tid & 15) * 4;
        f32x4 s = *(const f32x4*)&CTX[0][row * 68 + d4];
        s += *(const f32x4*)&CTX[1][row * 68 + d4];
        s += *(const f32x4*)&CTX[2][row * 68 + d4];
        s += *(const f32x4*)&CTX[3][row * 68 + d4];
        u16x4 o;
        o[0] = f2bfbits(s[0]); o[1] = f2bfbits(s[1]);
        o[2] = f2bfbits(s[2]); o[3] = f2bfbits(s[3]);
        *(u16x4*)&ctxb[((size_t)b * LL + q0 + row) * EE + h * HD + d4] = o;
    }
}

// ---------------------------------------------------------------------------
extern "C" void kernel_launch(void* const* d_in, const int* in_sizes, int n_in,
                              void* d_out, int out_size, void* d_ws, size_t ws_size,
                              hipStream_t stream)
{
    const float* x   = (const float*)d_in[0];
    const float* pe  = (const float*)d_in[1];
    const float* ipw = (const float*)d_in[2];
    const float* lpw = (const float*)d_in[3];
    const float* opw = (const float*)d_in[4];
    const float* opb = (const float*)d_in[5];
    const float* pbu = (const float*)d_in[6];
    const float* pbv = (const float*)d_in[7];

    float* out  = (float*)d_out;                          // (B,L,E)
    float* attn = (float*)d_out + (size_t)BB * LL * EE;   // (B,H,L,L)

    const size_t NQ = (size_t)BB * HH * LL * HD;  // 4194304
    u16* wsu  = (u16*)d_ws;
    u16* ctxb = wsu; wsu += (size_t)BB * LL * EE;         // 4194304
    u16* Qu   = wsu; wsu += NQ;
    u16* Qv   = wsu; wsu += NQ;
    u16* Kw   = wsu; wsu += NQ;
    u16* Vt   = wsu; wsu += NQ;
    u16* pkb  = wsu; wsu += (size_t)HH * PP * HD;         // 1048064
    u16* Xb   = wsu; wsu += 4194304;                      // (B*L,E) bf16
    u16* Pb   = wsu; wsu += 1048064;                      // (P,E) bf16
    u16* Wqb  = wsu; wsu += 786432;                       // (3E,E) bf16
    u16* Wpb  = wsu; wsu += 262144;                       // (E,E) bf16
    u16* Wob  = wsu; wsu += 262144;                       // (E,E) bf16

    cast_all<<<3200, 256, 0, stream>>>(x, pe, ipw, lpw, opw, Xb, Pb, Wqb, Wpb, Wob);
    qkv_kernel<<<dim3(12, 64), 256, 0, stream>>>(Xb, Wqb, pbu, pbv, Qu, Qv, Kw, Vt);
    posk_kernel<<<dim3(4, 16), 256, 0, stream>>>(Pb, Wpb, pkb);
    attn_kernel<<<dim3(64, 8, 8), 256, 0, stream>>>(Qu, Qv, Kw, Vt, pkb, attn, ctxb);
    outproj_kernel<<<dim3(4, 64), 256, 0, stream>>>(ctxb, opw ? Wob : Wob, opb, out);
}

// Round 3
// 523.346 us; speedup vs baseline: 1.3893x; 1.0341x over previous
//
#include <hip/hip_runtime.h>
#include <math.h>

#define BB 8
#define LL 1024
#define EE 512
#define HH 8
#define HD 64
#define PP 2047

static constexpr float SCALE = 0.04419417382415922f; // 1/sqrt(512)

typedef __bf16 bf16x8 __attribute__((ext_vector_type(8)));
typedef float f32x4 __attribute__((ext_vector_type(4)));
typedef unsigned short u16;
typedef u16 u16x8 __attribute__((ext_vector_type(8)));
typedef u16 u16x4 __attribute__((ext_vector_type(4)));

#define MFMA16(a, b, c) __builtin_amdgcn_mfma_f32_16x16x32_bf16(a, b, c, 0, 0, 0)

static __device__ __forceinline__ unsigned short f2bfbits(float f) {
    union { float f; unsigned u; } v; v.f = f;
    unsigned r = v.u + 0x7fffu + ((v.u >> 16) & 1u);
    return (unsigned short)(r >> 16);
}
static __device__ __forceinline__ float bfbits2f(unsigned short b) {
    union { unsigned u; float f; } v; v.u = ((unsigned)b) << 16;
    return v.f;
}

static __device__ __forceinline__ u16x8 cvt8(float4 lo, float4 hi) {
    u16x8 r;
    r[0] = f2bfbits(lo.x); r[1] = f2bfbits(lo.y);
    r[2] = f2bfbits(lo.z); r[3] = f2bfbits(lo.w);
    r[4] = f2bfbits(hi.x); r[5] = f2bfbits(hi.y);
    r[6] = f2bfbits(hi.z); r[7] = f2bfbits(hi.w);
    return r;
}

// async global(16B/lane) -> LDS, wave-uniform LDS base + lane*16
static __device__ __forceinline__ void gload_lds16(const u16* g, u16* l) {
    __builtin_amdgcn_global_load_lds(
        (const __attribute__((address_space(1))) unsigned int*)g,
        (__attribute__((address_space(3))) unsigned int*)l, 16, 0, 0);
}

// ---------------------------------------------------------------------------
// Fused one-shot fp32 -> bf16 cast of all GEMM inputs.
// cum: x 4194304 | pe 1048064 | ipw 786432 | lpw 262144 | opw 262144
// ---------------------------------------------------------------------------
__global__ __launch_bounds__(256) void cast_all(
    const float* __restrict__ x, const float* __restrict__ pe,
    const float* __restrict__ ipw, const float* __restrict__ lpw,
    const float* __restrict__ opw,
    u16* __restrict__ Xb, u16* __restrict__ Pb, u16* __restrict__ Wqb,
    u16* __restrict__ Wpb, u16* __restrict__ Wob)
{
    size_t e = ((size_t)blockIdx.x * 256 + threadIdx.x) * 8;
    const float* src; u16* dst; size_t off;
    if (e < 4194304)      { src = x;   dst = Xb;  off = e; }
    else if (e < 5242368) { src = pe;  dst = Pb;  off = e - 4194304; }
    else if (e < 6028800) { src = ipw; dst = Wqb; off = e - 5242368; }
    else if (e < 6290944) { src = lpw; dst = Wpb; off = e - 6028800; }
    else if (e < 6553088) { src = opw; dst = Wob; off = e - 6290944; }
    else return;
    float4 lo = *(const float4*)&src[off];
    float4 hi = *(const float4*)&src[off + 4];
    *(u16x8*)&dst[off] = cvt8(lo, hi);
}

// ---------------------------------------------------------------------------
// bf16 MFMA mainloop: C(128x128) = A(128xK) . B(128xK)^T rows, K=512.
// global_load_lds(16B) staging, linear LDS dest, XOR-swizzled global source
// + matching XOR on ds_read side (rule: both-sides-or-neither).
// acc[mt][nt][r] = C[m0 + wr*64 + mt*16 + g*4 + r][n0 + wc*64 + nt*16 + c16]
// ---------------------------------------------------------------------------
template<bool CLAMP>
static __device__ __forceinline__ void gemm128b(
    const u16* __restrict__ Ab, const u16* __restrict__ Bb,
    int m0, int n0, int amax, u16* As, u16* Bs, f32x4 (&acc)[4][4])
{
    const int tid = threadIdx.x;
    const int w = tid >> 6, lane = tid & 63;
    const int g = lane >> 4, c16 = lane & 15;
    const int wr = w >> 1, wc = w & 1;

#pragma unroll
    for (int i = 0; i < 4; i++)
#pragma unroll
        for (int j = 0; j < 4; j++) acc[i][j] = (f32x4){0.f, 0.f, 0.f, 0.f};

    // staging geometry: 16B unit U = j*256 + tid; row = U>>3, col-unit = U&7,
    // source col-unit swizzled by row&7; LDS stays linear (HW lane*16 order).
    int arow[4], brow[4], cs8[4], ldsu[4];
#pragma unroll
    for (int j = 0; j < 4; j++) {
        int U = j * 256 + tid;
        int row = U >> 3, cu = U & 7;
        cs8[j] = (cu ^ (row & 7)) * 8;
        int ar = m0 + row;
        if (CLAMP) ar = ar > amax ? amax : ar;
        arow[j] = ar;
        brow[j] = n0 + row;
        ldsu[j] = (j * 256 + (w << 6)) * 8; // wave-uniform LDS base (u16 elems)
    }

    for (int kt = 0; kt < EE; kt += 64) {
#pragma unroll
        for (int j = 0; j < 4; j++) {
            gload_lds16(Ab + (size_t)arow[j] * EE + kt + cs8[j], As + ldsu[j]);
            gload_lds16(Bb + (size_t)brow[j] * EE + kt + cs8[j], Bs + ldsu[j]);
        }
        __syncthreads(); // drains vmcnt -> tiles resident
#pragma unroll
        for (int kk = 0; kk < 2; kk++) {
            bf16x8 av[4], bv[4];
#pragma unroll
            for (int mt = 0; mt < 4; mt++) {
                int r0 = wr * 64 + mt * 16 + c16;
                av[mt] = *(const bf16x8*)&As[r0 * 64 + (((kk * 4 + g) ^ (r0 & 7)) << 3)];
            }
#pragma unroll
            for (int nt = 0; nt < 4; nt++) {
                int r0 = wc * 64 + nt * 16 + c16;
                bv[nt] = *(const bf16x8*)&Bs[r0 * 64 + (((kk * 4 + g) ^ (r0 & 7)) << 3)];
            }
#pragma unroll
            for (int mt = 0; mt < 4; mt++)
#pragma unroll
                for (int nt = 0; nt < 4; nt++)
                    acc[mt][nt] = MFMA16(av[mt], bv[nt], acc[mt][nt]);
        }
        __syncthreads(); // all reads done before next stage overwrites
    }
}

// ---------------------------------------------------------------------------
// merged qkv + posk. 1-D grid of 832 blocks:
//   bid < 768: qkv tile, XCD-clustered m-range (xcd = bid&7 owns m-tiles
//              xcd*8..xcd*8+7 -> x-panel + weights L2-resident per XCD)
//   bid >= 768: posk tile (64 blocks)
// ---------------------------------------------------------------------------
__global__ __launch_bounds__(256) void qkvpos_kernel(
    const u16* __restrict__ xb,       // (B*L, E) bf16
    const u16* __restrict__ wq,       // (3E, E) bf16
    const float* __restrict__ ubias,  // flat 512
    const float* __restrict__ vbias,  // flat 512
    unsigned short* __restrict__ Qu,  // (B,H,L,HD) bf16, (q+u)*scale
    unsigned short* __restrict__ Qv,  // (B,H,L,HD) bf16, (q+v)*scale
    unsigned short* __restrict__ Kw,  // (B,H,L,HD) bf16
    unsigned short* __restrict__ Vt,  // (B,H,HD,L) bf16 (transposed!)
    const u16* __restrict__ peb,      // (P, E) bf16
    const u16* __restrict__ wp,       // (E, E) bf16
    unsigned short* __restrict__ pko) // (H, P, HD) bf16
{
    __shared__ u16 As[128 * 64];
    __shared__ u16 Bs[128 * 64];
    const int bid = blockIdx.x;
    const int tid = threadIdx.x;
    const int w = tid >> 6, lane = tid & 63;
    const int g = lane >> 4, c16 = lane & 15;
    const int wr = w >> 1, wc = w & 1;
    f32x4 acc[4][4];

    if (bid < 768) {
        const int xcd = bid & 7, j = bid >> 3;
        const int m0 = (xcd * 8 + j / 12) * 128, n0 = (j % 12) * 128;
        gemm128b<false>(xb, wq, m0, n0, 0, As, Bs, acc);
#pragma unroll
        for (int mt = 0; mt < 4; mt++) {
#pragma unroll
            for (int r = 0; r < 4; r++) {
                int m = m0 + wr * 64 + mt * 16 + g * 4 + r;
                int b = m >> 10, l = m & 1023;
#pragma unroll
                for (int nt = 0; nt < 4; nt++) {
                    int n = n0 + wc * 64 + nt * 16 + c16;
                    int h = n / 192;
                    int rr = n - h * 192;
                    int cls = rr >> 6;
                    int d = rr & 63;
                    float v = acc[mt][nt][r];
                    if (cls == 0) {
                        size_t idx = ((size_t)(b * HH + h) * LL + l) * HD + d;
                        Qu[idx] = f2bfbits((v + ubias[h * 64 + d]) * SCALE);
                        Qv[idx] = f2bfbits((v + vbias[h * 64 + d]) * SCALE);
                    } else if (cls == 1) {
                        Kw[((size_t)(b * HH + h) * LL + l) * HD + d] = f2bfbits(v);
                    } else {
                        Vt[((size_t)(b * HH + h) * HD + d) * LL + l] = f2bfbits(v);
                    }
                }
            }
        }
    } else {
        const int j = bid - 768;
        const int m0 = (j >> 2) * 128, n0 = (j & 3) * 128;
        gemm128b<true>(peb, wp, m0, n0, PP - 1, As, Bs, acc);
#pragma unroll
        for (int mt = 0; mt < 4; mt++) {
#pragma unroll
            for (int r = 0; r < 4; r++) {
                int p = m0 + wr * 64 + mt * 16 + g * 4 + r;
                if (p >= PP) continue;
#pragma unroll
                for (int nt = 0; nt < 4; nt++) {
                    int n = n0 + wc * 64 + nt * 16 + c16;
                    int h = n >> 6, d = n & 63;
                    pko[((size_t)h * PP + p) * HD + d] = f2bfbits(acc[mt][nt][r]);
                }
            }
        }
    }
}

// ---------------------------------------------------------------------------
// outproj: (B*L,E)bf16 @ (E,E)^T bf16 + bias -> fp32 out. XCD-clustered,
// 1-D grid 256. nontemporal out stores (never re-read).
// ---------------------------------------------------------------------------
__global__ __launch_bounds__(256) void outproj_kernel(
    const u16* __restrict__ ctxb,   // (B*L, E) bf16
    const u16* __restrict__ wo,     // (E, E) bf16
    const float* __restrict__ bias, // (E,)
    float* __restrict__ out)        // (B*L, E)
{
    __shared__ u16 As[128 * 64];
    __shared__ u16 Bs[128 * 64];
    const int bid = blockIdx.x;
    const int xcd = bid & 7, j = bid >> 3;
    const int m0 = (xcd * 8 + (j >> 2)) * 128, n0 = (j & 3) * 128;
    f32x4 acc[4][4];
    gemm128b<false>(ctxb, wo, m0, n0, 0, As, Bs, acc);

    const int tid = threadIdx.x;
    const int w = tid >> 6, lane = tid & 63;
    const int g = lane >> 4, c16 = lane & 15;
    const int wr = w >> 1, wc = w & 1;

#pragma unroll
    for (int mt = 0; mt < 4; mt++) {
#pragma unroll
        for (int r = 0; r < 4; r++) {
            int m = m0 + wr * 64 + mt * 16 + g * 4 + r;
#pragma unroll
            for (int nt = 0; nt < 4; nt++) {
                int n = n0 + wc * 64 + nt * 16 + c16;
                __builtin_nontemporal_store(acc[mt][nt][r] + bias[n],
                                            &out[(size_t)m * EE + n]);
            }
        }
    }
}

// ---------------------------------------------------------------------------
// MFMA fused attention. 1-D grid 4096, XCD-clustered: xcd = bid&7 owns
// bh in [xcd*8, xcd*8+8), bh-sequential so per-XCD live set ~512KB (L2-fit).
// Block = (bh, 16 q-rows); 4 waves split k (256 each).
// logit[q,k] = Qu[q].K[k] + Qv[q].pk[k-q+1023]; softmax; attn write (NT); PV.
// LDS: BDG and CTX share one region (phases barrier-separated) -> ~20KB.
// ---------------------------------------------------------------------------
__global__ __launch_bounds__(256, 4) void attn_kernel(
    const unsigned short* __restrict__ Qu, const unsigned short* __restrict__ Qv,
    const unsigned short* __restrict__ Kw, const unsigned short* __restrict__ Vt,
    const unsigned short* __restrict__ pk,  // (H,P,HD) bf16
    float* __restrict__ attn,               // (B,H,L,L)
    u16* __restrict__ ctxb)                 // (B,L,E) bf16
{
    const int bid = blockIdx.x;
    const int xcd = bid & 7, jj = bid >> 3;
    const int bh = xcd * 8 + (jj >> 6);
    const int q0 = (jj & 63) * 16;
    const int b = bh >> 3, h = bh & 7;
    const int tid = threadIdx.x;
    const int w = tid >> 6, lane = tid & 63;
    const int g = lane >> 4, c16 = lane & 15;

    __shared__ __align__(16) unsigned char SH[4][4864]; // BDG (u16[16*152]) / CTX (f32[16*68])
    __shared__ float SMmax[4][16];
    __shared__ float SMsum[4][16];
    unsigned short* BDGw = (unsigned short*)SH[w];

    // resident A-fragments (A[m=lane&15][k=g*8+j]): direct 16B global loads
    const unsigned short* qub = Qu + ((size_t)bh * LL + q0 + c16) * HD + g * 8;
    const unsigned short* qvb = Qv + ((size_t)bh * LL + q0 + c16) * HD + g * 8;
    bf16x8 au0 = *(const bf16x8*)qub;
    bf16x8 au1 = *(const bf16x8*)(qub + 32);
    bf16x8 av0 = *(const bf16x8*)qvb;
    bf16x8 av1 = *(const bf16x8*)(qvb + 32);

    f32x4 lg[16];
#pragma unroll
    for (int t = 0; t < 16; t++) lg[t] = (f32x4){0.f, 0.f, 0.f, 0.f};

    const unsigned short* kbase  = Kw + (size_t)bh * LL * HD;
    const unsigned short* pkbase = pk + (size_t)h * PP * HD;

#pragma unroll
    for (int p = 0; p < 2; p++) {
        const int kp = w * 256 + p * 128;
        const int pstart = kp - q0 + 1008;  // window col 0 -> p index
        // BD window gemm: 16 q x 144 cols, staged bf16 in LDS
#pragma unroll
        for (int ct = 0; ct < 9; ct++) {
            int prow = pstart + ct * 16 + c16;
            prow = prow > (PP - 1) ? (PP - 1) : prow;  // col 143 pad, never gathered
            const unsigned short* pb = pkbase + (size_t)prow * HD + g * 8;
            f32x4 acc = (f32x4){0.f, 0.f, 0.f, 0.f};
            acc = MFMA16(av0, *(const bf16x8*)pb, acc);
            acc = MFMA16(av1, *(const bf16x8*)(pb + 32), acc);
#pragma unroll
            for (int r = 0; r < 4; r++)
                BDGw[(g * 4 + r) * 152 + ct * 16 + c16] = f2bfbits(acc[r]);
        }
        // AC: B-frag = K rows, direct global 16B loads
#pragma unroll
        for (int jt = 0; jt < 8; jt++) {
            const unsigned short* kb = kbase + (size_t)(kp + jt * 16 + c16) * HD + g * 8;
            int t = p * 8 + jt;
            lg[t] = MFMA16(au0, *(const bf16x8*)kb, lg[t]);
            lg[t] = MFMA16(au1, *(const bf16x8*)(kb + 32), lg[t]);
        }
        __syncthreads();
        // diagonal gather: BD[i][j] = BDG[i][j - i + 15]
#pragma unroll
        for (int jt = 0; jt < 8; jt++) {
            int t = p * 8 + jt;
#pragma unroll
            for (int r = 0; r < 4; r++) {
                int i = g * 4 + r;
                int c = jt * 16 + c16 - i + 15;
                lg[t][r] += bfbits2f(BDGw[i * 152 + c]);
            }
        }
        __syncthreads();
    }

    // ---- softmax over full 1024 keys ----
    float M[4], Sv[4], inv[4];
#pragma unroll
    for (int r = 0; r < 4; r++) {
        float m = lg[0][r];
#pragma unroll
        for (int t = 1; t < 16; t++) m = fmaxf(m, lg[t][r]);
        M[r] = m;
    }
#pragma unroll
    for (int off = 8; off >= 1; off >>= 1)
#pragma unroll
        for (int r = 0; r < 4; r++) M[r] = fmaxf(M[r], __shfl_xor(M[r], off, 16));
    if (c16 == 0) {
#pragma unroll
        for (int r = 0; r < 4; r++) SMmax[w][g * 4 + r] = M[r];
    }
    __syncthreads();
#pragma unroll
    for (int r = 0; r < 4; r++) {
        int row = g * 4 + r;
        M[r] = fmaxf(fmaxf(SMmax[0][row], SMmax[1][row]),
                     fmaxf(SMmax[2][row], SMmax[3][row]));
        Sv[r] = 0.f;
    }
#pragma unroll
    for (int t = 0; t < 16; t++)
#pragma unroll
        for (int r = 0; r < 4; r++) {
            float e = __expf(lg[t][r] - M[r]);
            lg[t][r] = e;
            Sv[r] += e;
        }
#pragma unroll
    for (int off = 8; off >= 1; off >>= 1)
#pragma unroll
        for (int r = 0; r < 4; r++) Sv[r] += __shfl_xor(Sv[r], off, 16);
    if (c16 == 0) {
#pragma unroll
        for (int r = 0; r < 4; r++) SMsum[w][g * 4 + r] = Sv[r];
    }
    __syncthreads();
#pragma unroll
    for (int r = 0; r < 4; r++) {
        int row = g * 4 + r;
        inv[r] = 1.0f / (SMsum[0][row] + SMsum[1][row] + SMsum[2][row] + SMsum[3][row]);
    }

    // ---- normalize + write attn (nontemporal: don't evict K/V/pk) ----
    float* arow = attn + (size_t)bh * LL * LL;
#pragma unroll
    for (int t = 0; t < 16; t++)
#pragma unroll
        for (int r = 0; r < 4; r++) {
            float pr = lg[t][r] * inv[r];
            lg[t][r] = pr;
            __builtin_nontemporal_store(
                pr, &arow[(size_t)(q0 + g * 4 + r) * LL + w * 256 + t * 16 + c16]);
        }

    // ---- PV: ctx[q][d] = sum_k P[q,k] V[k,d], B from transposed V ----
    f32x4 cacc[4];
#pragma unroll
    for (int nt = 0; nt < 4; nt++) cacc[nt] = (f32x4){0.f, 0.f, 0.f, 0.f};

#pragma unroll
    for (int p = 0; p < 2; p++) {
        const int kp = w * 256 + p * 128;
        __syncthreads();
        // stage P (C-layout -> A-layout via LDS), bf16
#pragma unroll
        for (int jt = 0; jt < 8; jt++) {
            int t = p * 8 + jt;
#pragma unroll
            for (int r = 0; r < 4; r++)
                BDGw[(g * 4 + r) * 152 + jt * 16 + c16] = f2bfbits(lg[t][r]);
        }
        __syncthreads();
        bf16x8 pa[4];
#pragma unroll
        for (int kk = 0; kk < 4; kk++)
            pa[kk] = *(const bf16x8*)&BDGw[c16 * 152 + kk * 32 + g * 8];
#pragma unroll
        for (int kk = 0; kk < 4; kk++) {
#pragma unroll
            for (int nt = 0; nt < 4; nt++) {
                const unsigned short* vb =
                    Vt + ((size_t)bh * HD + nt * 16 + c16) * LL + kp + kk * 32 + g * 8;
                cacc[nt] = MFMA16(pa[kk], *(const bf16x8*)vb, cacc[nt]);
            }
        }
    }

    // ---- cross-wave ctx reduction (CTX aliases BDG region; barrier-safe) ----
    __syncthreads();
    {
        float* CTXw = (float*)SH[w];
#pragma unroll
        for (int nt = 0; nt < 4; nt++)
#pragma unroll
            for (int r = 0; r < 4; r++)
                CTXw[(g * 4 + r) * 68 + nt * 16 + c16] = cacc[nt][r];
    }
    __syncthreads();
    {
        int row = tid >> 4, d4 = (tid & 15) * 4;
        f32x4 s = *(const f32x4*)&((const float*)SH[0])[row * 68 + d4];
        s += *(const f32x4*)&((const float*)SH[1])[row * 68 + d4];
        s += *(const f32x4*)&((const float*)SH[2])[row * 68 + d4];
        s += *(const f32x4*)&((const float*)SH[3])[row * 68 + d4];
        u16x4 o;
        o[0] = f2bfbits(s[0]); o[1] = f2bfbits(s[1]);
        o[2] = f2bfbits(s[2]); o[3] = f2bfbits(s[3]);
        *(u16x4*)&ctxb[((size_t)b * LL + q0 + row) * EE + h * HD + d4] = o;
    }
}

// ---------------------------------------------------------------------------
extern "C" void kernel_launch(void* const* d_in, const int* in_sizes, int n_in,
                              void* d_out, int out_size, void* d_ws, size_t ws_size,
                              hipStream_t stream)
{
    const float* x   = (const float*)d_in[0];
    const float* pe  = (const float*)d_in[1];
    const float* ipw = (const float*)d_in[2];
    const float* lpw = (const float*)d_in[3];
    const float* opw = (const float*)d_in[4];
    const float* opb = (const float*)d_in[5];
    const float* pbu = (const float*)d_in[6];
    const float* pbv = (const float*)d_in[7];

    float* out  = (float*)d_out;                          // (B,L,E)
    float* attn = (float*)d_out + (size_t)BB * LL * EE;   // (B,H,L,L)

    const size_t NQ = (size_t)BB * HH * LL * HD;  // 4194304
    u16* wsu  = (u16*)d_ws;
    u16* ctxb = wsu; wsu += (size_t)BB * LL * EE;         // 4194304
    u16* Qu   = wsu; wsu += NQ;
    u16* Qv   = wsu; wsu += NQ;
    u16* Kw   = wsu; wsu += NQ;
    u16* Vt   = wsu; wsu += NQ;
    u16* pkb  = wsu; wsu += (size_t)HH * PP * HD;         // 1048064
    u16* Xb   = wsu; wsu += 4194304;                      // (B*L,E) bf16
    u16* Pb   = wsu; wsu += 1048064;                      // (P,E) bf16
    u16* Wqb  = wsu; wsu += 786432;                       // (3E,E) bf16
    u16* Wpb  = wsu; wsu += 262144;                       // (E,E) bf16
    u16* Wob  = wsu; wsu += 262144;                       // (E,E) bf16

    cast_all<<<3200, 256, 0, stream>>>(x, pe, ipw, lpw, opw, Xb, Pb, Wqb, Wpb, Wob);
    qkvpos_kernel<<<832, 256, 0, stream>>>(Xb, Wqb, pbu, pbv, Qu, Qv, Kw, Vt,
                                           Pb, Wpb, pkb);
    attn_kernel<<<4096, 256, 0, stream>>>(Qu, Qv, Kw, Vt, pkb, attn, ctxb);
    outproj_kernel<<<256, 256, 0, stream>>>(ctxb, Wob, opb, out);
}